// Round 1
// baseline (737.160 us; speedup 1.0000x reference)
//
#include <hip/hip_runtime.h>
#include <stdint.h>

// ---------------------------------------------------------------------------
// StyleBlock (StyleGAN2 modulated conv 3x3 + noise + bias + LeakyReLU(0.2))
// B=16, Cin=Cout=512, H=W=64, K=3.
//
// Strategy:
//   A[b,ci]   = w @ (w_style/sqrt(512)).T + b_style          (k_style)
//   S[co,ci]  = sum_t w_conv[co,ci,t]^2                      (k_s2)
//   demod     = rsqrt(c^2 * sum_ci S*A^2 + eps)              (k_demod)
//   wpack     = bf16(w_conv * c_conv), LDS-ready layout      (k_wpack, batch-indep!)
//   conv      = MFMA implicit gemm, A folded into x staging,
//               demod/noise/bias/leaky in epilogue           (k_conv)
// ---------------------------------------------------------------------------

typedef __attribute__((ext_vector_type(8))) short s16x8;
typedef __attribute__((ext_vector_type(4))) float f32x4;

constexpr int CIN = 512, COUT = 512, WD = 512, HW = 4096;
constexpr float C_LIN  = 0.04419417382415922f;    // 1/sqrt(512)
constexpr float C_CONV = 0.014731391274719739f;   // 1/sqrt(4608)
constexpr float CC2    = 1.0f / 4608.0f;          // C_CONV^2
constexpr int WPITCH = 130;                       // co pitch in 16B cells (pad 128->130)
constexpr int SEGC   = 4736;                      // 16B cells per (cotile,chunk) segment (9*4*130=4680 used)

__device__ __forceinline__ unsigned short f2bf(float f) {
  union { float f; unsigned int u; } v; v.f = f;
  unsigned int u = v.u + 0x7FFFu + ((v.u >> 16) & 1u);   // round-to-nearest-even
  return (unsigned short)(u >> 16);
}

// ---------------- k_style: A[b,ci] = w[b,:] . w_style[ci,:] * c + b_style[ci]
__global__ void k_style(const float* __restrict__ w, const float* __restrict__ w_style,
                        const float* __restrict__ b_style, float* __restrict__ A) {
  __shared__ float wl[WD];
  const int b = blockIdx.x, tid = threadIdx.x;
  for (int i = tid; i < WD; i += 256) wl[i] = w[b * WD + i];
  __syncthreads();
  for (int ci = tid; ci < CIN; ci += 256) {
    const float4* row = (const float4*)(w_style + (size_t)ci * WD);
    float acc = 0.f;
    for (int k = 0; k < WD / 4; ++k) {
      float4 v = row[k];
      acc += v.x * wl[4*k] + v.y * wl[4*k+1] + v.z * wl[4*k+2] + v.w * wl[4*k+3];
    }
    A[b * CIN + ci] = acc * C_LIN + b_style[ci];
  }
}

// ---------------- k_s2: S[co,ci] = sum_t w_conv[co,ci,t]^2
__global__ void k_s2(const float* __restrict__ w_conv, float* __restrict__ S) {
  const int co = blockIdx.x, ci = threadIdx.x;
  const float* p = w_conv + ((size_t)co * CIN + ci) * 9;
  float s = 0.f;
#pragma unroll
  for (int t = 0; t < 9; ++t) { float v = p[t]; s += v * v; }
  S[co * CIN + ci] = s;
}

// ---------------- k_demod: demod[b,co] = rsqrt(c^2 * sum_ci S[co,ci]*A[b,ci]^2 + eps)
__global__ void k_demod(const float* __restrict__ S, const float* __restrict__ A,
                        float* __restrict__ demod) {
  __shared__ float a2[CIN];
  const int b = blockIdx.x, co = threadIdx.x;
  for (int i = threadIdx.x; i < CIN; i += 512) { float a = A[b * CIN + i]; a2[i] = a * a; }
  __syncthreads();
  float acc = 0.f;
  const float4* srow = (const float4*)(S + (size_t)co * CIN);
  for (int k = 0; k < CIN / 4; ++k) {
    float4 v = srow[k];
    acc += v.x * a2[4*k] + v.y * a2[4*k+1] + v.z * a2[4*k+2] + v.w * a2[4*k+3];
  }
  demod[b * COUT + co] = rsqrtf(CC2 * acc + 1e-8f);
}

// ---------------- k_wpack: bf16(w_conv * c_conv) into LDS-ready layout.
// segment (ct*16+ch) of SEGC 16B cells; cell (t*4+s)*130+co holds ci = ch*32+s*8+0..7
__global__ void k_wpack(const float* __restrict__ w_conv, unsigned short* __restrict__ wpack) {
  int gid = blockIdx.x * 256 + threadIdx.x;        // 294912 total
  int co = gid & 127; int r = gid >> 7;
  int s = r & 3; r >>= 2;
  int t = r % 9; r /= 9;
  int ch = r & 15; int ct = r >> 4;
  const int co_g = ct * 128 + co;
  const int ci0 = ch * 32 + s * 8;
  union { unsigned short u[8]; uint4 v; } pk;
#pragma unroll
  for (int j = 0; j < 8; ++j)
    pk.u[j] = f2bf(w_conv[((size_t)co_g * CIN + ci0 + j) * 9 + t] * C_CONV);
  size_t cell = (size_t)(ct * 16 + ch) * SEGC + (t * 4 + s) * WPITCH + co;
  ((uint4*)wpack)[cell] = pk.v;
}

// ---------------- k_conv: the main MFMA conv
// grid (16 sp, 4 cotile, 16 b), 512 threads (8 waves = 2 co-halves x 4 rows)
__global__ __launch_bounds__(512, 1) void k_conv(
    const float* __restrict__ x, const unsigned short* __restrict__ wpack,
    const float* __restrict__ A, const float* __restrict__ demod,
    const float* __restrict__ noise, const float* __restrict__ scale_noise,
    const float* __restrict__ bias, float* __restrict__ out) {

  __shared__ __align__(16) unsigned short x_lds[6 * 4 * 66 * 8];   // 25344 B
  __shared__ __align__(16) unsigned short w_lds[SEGC * 8];         // 75776 B
  __shared__ float As_l[CIN];
  __shared__ float dm_l[128];
  __shared__ float bi_l[128];

  const int b = blockIdx.z, ct = blockIdx.y, sp = blockIdx.x;
  const int r0 = sp * 4, co0 = ct * 128;
  const int tid = threadIdx.x, lane = tid & 63, wave = tid >> 6;
  const int wm = wave & 1;       // co half (0..1) -> 64 co
  const int wn = wave >> 1;      // output row within tile (0..3)
  const int l15 = lane & 15, l4 = lane >> 4;

  for (int i = tid; i < CIN; i += 512) As_l[i] = A[b * CIN + i];
  if (tid < 128) dm_l[tid] = demod[b * COUT + co0 + tid];
  else if (tid < 256) bi_l[tid - 128] = bias[co0 + tid - 128];
  __syncthreads();

  f32x4 acc[4][4];
#pragma unroll
  for (int m = 0; m < 4; ++m)
#pragma unroll
    for (int f = 0; f < 4; ++f) acc[m][f] = (f32x4){0.f, 0.f, 0.f, 0.f};

  for (int ch = 0; ch < 16; ++ch) {
    const int ci_base = ch * 32;
    // ---- stage x tile: cells (rr*4+s)*66 + c ; content = bf16(x * A), halo zeros
    for (int idx = tid; idx < 1584; idx += 512) {
      int c = idx % 66; int rs = idx / 66;
      int s = rs & 3, rr = rs >> 2;
      int rg = r0 + rr - 1, cg = c - 1;
      union { unsigned short u[8]; uint4 v; } pk;
      if ((unsigned)rg < 64u && (unsigned)cg < 64u) {
        const float* xp = x + ((size_t)(b * CIN + ci_base + s * 8)) * HW + rg * 64 + cg;
#pragma unroll
        for (int j = 0; j < 8; ++j)
          pk.u[j] = f2bf(xp[(size_t)j * HW] * As_l[ci_base + s * 8 + j]);
      } else {
#pragma unroll
        for (int j = 0; j < 8; ++j) pk.u[j] = 0;
      }
      *(uint4*)(x_lds + idx * 8) = pk.v;
    }
    // ---- stage weights: plain 16B copy of pre-packed segment
    {
      const uint4* wsrc = (const uint4*)wpack + (size_t)(ct * 16 + ch) * SEGC;
      uint4* wdst = (uint4*)w_lds;
      for (int idx = tid; idx < SEGC; idx += 512) wdst[idx] = wsrc[idx];
    }
    __syncthreads();

    // ---- compute: 9 taps, K=32 per tap
#pragma unroll
    for (int t = 0; t < 9; ++t) {
      const int dh = t / 3, dw = t % 3;
      s16x8 afr[4], bfr[4];
#pragma unroll
      for (int m = 0; m < 4; ++m) {
        int co_l = wm * 64 + m * 16 + l15;
        afr[m] = *(const s16x8*)(w_lds + ((t * 4 + l4) * WPITCH + co_l) * 8);
      }
#pragma unroll
      for (int f = 0; f < 4; ++f) {
        int cc = f * 16 + l15 + dw;
        int rrw = wn + dh;
        bfr[f] = *(const s16x8*)(x_lds + ((rrw * 4 + l4) * 66 + cc) * 8);
      }
#pragma unroll
      for (int m = 0; m < 4; ++m)
#pragma unroll
        for (int f = 0; f < 4; ++f)
          acc[m][f] = __builtin_amdgcn_mfma_f32_16x16x32_bf16(afr[m], bfr[f], acc[m][f], 0, 0, 0);
    }
    __syncthreads();
  }

  // ---- epilogue: demod, noise, bias, leaky relu
  const float sn = scale_noise[0];
  const int row = r0 + wn;
  float nz[4];
#pragma unroll
  for (int f = 0; f < 4; ++f) nz[f] = sn * noise[b * HW + row * 64 + f * 16 + l15];
#pragma unroll
  for (int m = 0; m < 4; ++m) {
#pragma unroll
    for (int reg = 0; reg < 4; ++reg) {
      int co_l = wm * 64 + m * 16 + l4 * 4 + reg;
      float d = dm_l[co_l], bv = bi_l[co_l];
      float* op = out + ((size_t)(b * COUT + co0 + co_l)) * HW + row * 64;
#pragma unroll
      for (int f = 0; f < 4; ++f) {
        float v = d * acc[m][f][reg] + nz[f] + bv;
        op[f * 16 + l15] = (v >= 0.f) ? v : 0.2f * v;
      }
    }
  }
}

// ---------------------------------------------------------------------------
extern "C" void kernel_launch(void* const* d_in, const int* in_sizes, int n_in,
                              void* d_out, int out_size, void* d_ws, size_t ws_size,
                              hipStream_t stream) {
  (void)in_sizes; (void)n_in; (void)out_size; (void)ws_size;
  const float* x           = (const float*)d_in[0];
  const float* w           = (const float*)d_in[1];
  const float* noise       = (const float*)d_in[2];
  const float* w_style     = (const float*)d_in[3];
  const float* b_style     = (const float*)d_in[4];
  const float* w_conv      = (const float*)d_in[5];
  const float* scale_noise = (const float*)d_in[6];
  const float* bias        = (const float*)d_in[7];
  float* out = (float*)d_out;

  char* ws = (char*)d_ws;
  float* A     = (float*)ws;                          // 32 KB
  float* S     = (float*)(ws + (32u << 10));          // 1 MB
  float* demod = (float*)(ws + (32u << 10) + (1u << 20));
  unsigned short* wpack = (unsigned short*)(ws + (2u << 20));  // ~4.85 MB

  k_style<<<16, 256, 0, stream>>>(w, w_style, b_style, A);
  k_s2<<<512, 512, 0, stream>>>(w_conv, S);
  k_demod<<<16, 512, 0, stream>>>(S, A, demod);
  k_wpack<<<1152, 256, 0, stream>>>(w_conv, wpack);
  k_conv<<<dim3(16, 4, 16), 512, 0, stream>>>(x, wpack, A, demod, noise, scale_noise, bias, out);
}

// Round 2
// 499.451 us; speedup vs baseline: 1.4759x; 1.4759x over previous
//
#include <hip/hip_runtime.h>
#include <stdint.h>

// ---------------------------------------------------------------------------
// StyleBlock: modulated conv3x3 + noise + bias + LeakyReLU. B=16,C=512,HW=64².
// R2: precomputed bf16 operands (xt = x*A transposed+haloed; wpack padded segs),
//     k_conv stages via global_load_lds only, 2 blocks/CU (79.6KB LDS).
// ---------------------------------------------------------------------------

typedef __attribute__((ext_vector_type(8))) short s16x8;
typedef __attribute__((ext_vector_type(4))) float f32x4;

constexpr int CIN = 512, COUT = 512, WD = 512, HW = 4096;
constexpr float C_LIN  = 0.04419417382415922f;    // 1/sqrt(512)
constexpr float C_CONV = 0.014731391274719739f;   // 1/sqrt(4608)
constexpr float CC2    = 1.0f / 4608.0f;

// ws layout (bytes):
//   A      @ 0         (32 KB)
//   S      @ 32768     (1 MB)
//   demod  @ 1081344   (32 KB)
//   wpack  @ 1310720   (4.5 MB: 128 segs x 2304 cells x 16B)
//   xt     @ 6291456   (69.2 MB: 256 x 16896 cells x 16B) + 4KB pad
constexpr size_t WS_A = 0, WS_S = 32768, WS_DM = 1081344;
constexpr size_t WS_WP = 1310720, WS_XT = 6291456;

__device__ __forceinline__ unsigned short f2bf(float f) {
  union { float f; unsigned int u; } v; v.f = f;
  unsigned int u = v.u + 0x7FFFu + ((v.u >> 16) & 1u);
  return (unsigned short)(u >> 16);
}

__device__ __forceinline__ void gload16(const void* g, void* l) {
  __builtin_amdgcn_global_load_lds((const __attribute__((address_space(1))) void*)g,
                                   (__attribute__((address_space(3))) void*)l, 16, 0, 0);
}

// ---------------- k_style: A[b,ci] = w[b,:].w_style[ci,:]*C_LIN + b_style[ci]
__global__ void k_style(const float* __restrict__ w, const float* __restrict__ wsty,
                        const float* __restrict__ bs, float* __restrict__ A) {
  __shared__ float wl[WD];
  __shared__ float red[256];
  const int ci0 = blockIdx.x * 64, b = blockIdx.y, tid = threadIdx.x;
  for (int i = tid; i < WD; i += 256) wl[i] = w[b * WD + i];
  __syncthreads();
  const int ci_l = tid & 63, part = tid >> 6;
  const float4* row = (const float4*)(wsty + (size_t)(ci0 + ci_l) * WD + part * 128);
  float acc = 0.f;
#pragma unroll
  for (int k = 0; k < 32; ++k) {
    float4 v = row[k];
    acc += v.x * wl[part*128 + 4*k] + v.y * wl[part*128 + 4*k+1]
         + v.z * wl[part*128 + 4*k+2] + v.w * wl[part*128 + 4*k+3];
  }
  red[tid] = acc;
  __syncthreads();
  if (part == 0)
    A[b * CIN + ci0 + ci_l] =
        (red[ci_l] + red[64+ci_l] + red[128+ci_l] + red[192+ci_l]) * C_LIN + bs[ci0 + ci_l];
}

// ---------------- k_s2: S[co,ci] = sum_t w_conv[co,ci,t]^2
__global__ void k_s2(const float* __restrict__ w_conv, float* __restrict__ S) {
  const int co = blockIdx.x, ci = threadIdx.x;
  const float* p = w_conv + ((size_t)co * CIN + ci) * 9;
  float s = 0.f;
#pragma unroll
  for (int t = 0; t < 9; ++t) { float v = p[t]; s += v * v; }
  S[co * CIN + ci] = s;
}

// ---------------- k_demod: demod[b,co] = rsqrt(CC2 * sum_ci S*A^2 + eps)
__global__ void k_demod(const float* __restrict__ S, const float* __restrict__ A,
                        float* __restrict__ dm) {
  __shared__ float a2[CIN];
  __shared__ float red[256];
  const int co0 = blockIdx.x * 32, b = blockIdx.y, tid = threadIdx.x;
  for (int i = tid; i < CIN; i += 256) { float a = A[b * CIN + i]; a2[i] = a * a; }
  __syncthreads();
  const int co_l = tid & 31, part = tid >> 5;
  const float4* row = (const float4*)(S + (size_t)(co0 + co_l) * CIN + part * 64);
  float acc = 0.f;
#pragma unroll
  for (int k = 0; k < 16; ++k) {
    float4 v = row[k];
    acc += v.x * a2[part*64 + 4*k] + v.y * a2[part*64 + 4*k+1]
         + v.z * a2[part*64 + 4*k+2] + v.w * a2[part*64 + 4*k+3];
  }
  red[tid] = acc;
  __syncthreads();
  if (tid < 32) {
    float s_ = 0.f;
#pragma unroll
    for (int p = 0; p < 8; ++p) s_ += red[p * 32 + tid];
    dm[b * COUT + co0 + tid] = rsqrtf(CC2 * s_ + 1e-8f);
  }
}

// ---------------- k_wpack: seg(ct,ch): cell (t*4+s)*64+co = bf16(w_conv*C_CONV), ci=ch*32+s*8+j
__global__ void k_wpack(const float* __restrict__ wc, uint4* __restrict__ wp) {
  __shared__ float wt[64][289];
  const int ct = blockIdx.x, ch = blockIdx.y, tid = threadIdx.x;
  const int co0 = ct * 64, ci0 = ch * 32;
  for (int i = tid; i < 64 * 288; i += 256) {
    int co = i / 288, r = i - co * 288;
    wt[co][r] = wc[(size_t)(co0 + co) * 4608 + (size_t)ci0 * 9 + r];
  }
  __syncthreads();
  uint4* seg = wp + (size_t)(ct * 16 + ch) * 2304;
  for (int c = tid; c < 2304; c += 256) {
    int t = c >> 8, rem = c & 255, s = rem >> 6, co = rem & 63;
    union { unsigned short u[8]; uint4 v; } pk;
#pragma unroll
    for (int j = 0; j < 8; ++j) pk.u[j] = f2bf(wt[co][(s*8 + j) * 9 + t] * C_CONV);
    seg[c] = pk.v;
  }
}

// ---------------- k_xt: xt[b][ch][row][s][66 cells] = bf16(x * A), col-halo zeros
__global__ void k_xt(const float* __restrict__ x, const float* __restrict__ A,
                     uint4* __restrict__ xt) {
  __shared__ float tile[32][132];
  __shared__ float As[32];
  const int ch = blockIdx.x, b = blockIdx.y, tid = threadIdx.x;
  const int ci0 = ch * 32;
  if (tid < 32) As[tid] = A[b * CIN + ci0 + tid];
  uint4* dst = xt + (size_t)(b * 16 + ch) * 16896;
  for (int i = tid; i < 256; i += 256) {
    int row = i >> 2, s = i & 3;
    uint4 z = {0, 0, 0, 0};
    dst[(row * 4 + s) * 66] = z;
    dst[(row * 4 + s) * 66 + 65] = z;
  }
  __syncthreads();
  for (int pt = 0; pt < 32; ++pt) {
    for (int i = tid; i < 4096; i += 256) {
      int ci = i >> 7, px = i & 127;
      tile[ci][px] = x[((size_t)(b * CIN + ci0 + ci)) * HW + pt * 128 + px] * As[ci];
    }
    __syncthreads();
    for (int c2 = tid; c2 < 512; c2 += 256) {
      int s = c2 >> 7, px = c2 & 127, rl = px >> 6, col = px & 63, row = pt * 2 + rl;
      union { unsigned short u[8]; uint4 v; } pk;
#pragma unroll
      for (int j = 0; j < 8; ++j) pk.u[j] = f2bf(tile[s*8 + j][px]);
      dst[(row * 4 + s) * 66 + 1 + col] = pk.v;
    }
    __syncthreads();
  }
}

// ---------------- k_conv: 64co x 512px tiles, ci-chunk 32, pure-DMA staging
__global__ __launch_bounds__(512, 4) void k_conv(
    const uint4* __restrict__ xt, const uint4* __restrict__ wp,
    const float* __restrict__ demod, const float* __restrict__ noise,
    const float* __restrict__ sn_, const float* __restrict__ bias,
    float* __restrict__ out) {

  __shared__ __align__(16) uint4 x_lds[2640];   // 10 rows x 4 s x 66 cells
  __shared__ __align__(16) uint4 w_lds[2304];   // 9 t x 4 s x 64 co
  __shared__ float dm_l[64], bi_l[64];

  const int sp = blockIdx.x, ct = blockIdx.y, b = blockIdx.z;
  const int r0 = sp * 8, co0 = ct * 64;
  const int tid = threadIdx.x, lane = tid & 63, wave = tid >> 6;
  const int l15 = lane & 15, l4 = lane >> 4;

  if (tid < 64) dm_l[tid] = demod[b * COUT + co0 + tid];
  else if (tid < 128) bi_l[tid - 64] = bias[co0 + tid - 64];
  // zero halo rows (only boundary sp; cells never touched by staging)
  if (sp == 0) for (int i = tid; i < 264; i += 512) x_lds[i] = (uint4){0, 0, 0, 0};
  if (sp == 7) for (int i = tid; i < 264; i += 512) x_lds[2376 + i] = (uint4){0, 0, 0, 0};

  const int lo = (r0 - 1 > 0) ? r0 - 1 : 0;
  const int hi = (r0 + 8 < 63) ? r0 + 8 : 63;
  const int cells = (hi - lo + 1) * 264;
  const int dst0 = (lo - (r0 - 1)) * 264;      // 0 or 264
  const int nI = cells >> 6, tail = cells & 63;

  f32x4 acc[4][4];
#pragma unroll
  for (int m = 0; m < 4; ++m)
#pragma unroll
    for (int f = 0; f < 4; ++f) acc[m][f] = (f32x4){0.f, 0.f, 0.f, 0.f};
  __syncthreads();

  for (int ch = 0; ch < 16; ++ch) {
    const uint4* xsrc = xt + ((size_t)(b * 16 + ch) * 64 + lo) * 264;
    const uint4* wsrc = wp + (size_t)(ct * 16 + ch) * 2304;
    for (int i = wave; i < nI; i += 8)
      gload16(xsrc + i * 64 + lane, &x_lds[dst0 + i * 64]);
    if (tid < tail) x_lds[dst0 + nI * 64 + tid] = xsrc[nI * 64 + tid];
    for (int i = wave; i < 36; i += 8)
      gload16(wsrc + i * 64 + lane, &w_lds[i * 64]);
    __syncthreads();

#pragma unroll
    for (int t = 0; t < 9; ++t) {
      const int dh = t / 3, dw = t - dh * 3;
      s16x8 afr[4], bfr[4];
#pragma unroll
      for (int m = 0; m < 4; ++m)
        afr[m] = *(const s16x8*)&w_lds[(t * 4 + l4) * 64 + m * 16 + l15];
#pragma unroll
      for (int f = 0; f < 4; ++f)
        bfr[f] = *(const s16x8*)&x_lds[((wave + dh) * 4 + l4) * 66 + f * 16 + l15 + dw];
#pragma unroll
      for (int m = 0; m < 4; ++m)
#pragma unroll
        for (int f = 0; f < 4; ++f)
          acc[m][f] = __builtin_amdgcn_mfma_f32_16x16x32_bf16(afr[m], bfr[f], acc[m][f], 0, 0, 0);
    }
    __syncthreads();
  }

  const float sn = sn_[0];
  const int row = r0 + wave;
  float nz[4];
#pragma unroll
  for (int f = 0; f < 4; ++f) nz[f] = sn * noise[b * HW + row * 64 + f * 16 + l15];
#pragma unroll
  for (int m = 0; m < 4; ++m) {
#pragma unroll
    for (int reg = 0; reg < 4; ++reg) {
      const int co_l = m * 16 + l4 * 4 + reg;
      const float d = dm_l[co_l], bv = bi_l[co_l];
      float* op = out + ((size_t)(b * COUT + co0 + co_l)) * HW + row * 64;
#pragma unroll
      for (int f = 0; f < 4; ++f) {
        float v = d * acc[m][f][reg] + nz[f] + bv;
        op[f * 16 + l15] = (v >= 0.f) ? v : 0.2f * v;
      }
    }
  }
}

// ---------------------------------------------------------------------------
extern "C" void kernel_launch(void* const* d_in, const int* in_sizes, int n_in,
                              void* d_out, int out_size, void* d_ws, size_t ws_size,
                              hipStream_t stream) {
  (void)in_sizes; (void)n_in; (void)out_size; (void)ws_size;
  const float* x           = (const float*)d_in[0];
  const float* w           = (const float*)d_in[1];
  const float* noise       = (const float*)d_in[2];
  const float* w_style     = (const float*)d_in[3];
  const float* b_style     = (const float*)d_in[4];
  const float* w_conv      = (const float*)d_in[5];
  const float* scale_noise = (const float*)d_in[6];
  const float* bias        = (const float*)d_in[7];
  float* out = (float*)d_out;

  char* ws = (char*)d_ws;
  float* A     = (float*)(ws + WS_A);
  float* S     = (float*)(ws + WS_S);
  float* demod = (float*)(ws + WS_DM);
  uint4* wpack = (uint4*)(ws + WS_WP);
  uint4* xt    = (uint4*)(ws + WS_XT);

  k_style<<<dim3(8, 16), 256, 0, stream>>>(w, w_style, b_style, A);
  k_s2<<<512, 512, 0, stream>>>(w_conv, S);
  k_demod<<<dim3(16, 16), 256, 0, stream>>>(S, A, demod);
  k_wpack<<<dim3(8, 16), 256, 0, stream>>>(w_conv, wpack);
  k_xt<<<dim3(16, 16), 256, 0, stream>>>(x, A, xt);
  k_conv<<<dim3(8, 8, 16), 512, 0, stream>>>(xt, wpack, demod, noise, scale_noise, bias, out);
}

// Round 3
// 494.521 us; speedup vs baseline: 1.4907x; 1.0100x over previous
//
#include <hip/hip_runtime.h>
#include <stdint.h>

// ---------------------------------------------------------------------------
// StyleBlock: modulated conv3x3 + noise + bias + LeakyReLU. B=16,C=512,HW=64².
// R3: w_lds pitch 66 (bank-conflict-free afr), LDS-free k_xt, fused k_s2+wpack.
// ---------------------------------------------------------------------------

typedef __attribute__((ext_vector_type(8))) short s16x8;
typedef __attribute__((ext_vector_type(4))) float f32x4;

constexpr int CIN = 512, COUT = 512, WD = 512, HW = 4096;
constexpr float C_LIN  = 0.04419417382415922f;    // 1/sqrt(512)
constexpr float C_CONV = 0.014731391274719739f;   // 1/sqrt(4608)
constexpr float CC2    = 1.0f / 4608.0f;

// wpack seg: 9t x 4s x pitch66 cells (2376 used), stride 2432 (38*64)
constexpr int WSEG = 2432;

// ws layout (bytes): A@0 (32KB) | S@32768 (1MB) | demod@1081344 (32KB)
//                    wpack@1310720 (4.98MB) | xt@6291456 (69.2MB)
constexpr size_t WS_A = 0, WS_S = 32768, WS_DM = 1081344;
constexpr size_t WS_WP = 1310720, WS_XT = 6291456;

__device__ __forceinline__ unsigned short f2bf(float f) {
  union { float f; unsigned int u; } v; v.f = f;
  unsigned int u = v.u + 0x7FFFu + ((v.u >> 16) & 1u);
  return (unsigned short)(u >> 16);
}

__device__ __forceinline__ void gload16(const void* g, void* l) {
  __builtin_amdgcn_global_load_lds((const __attribute__((address_space(1))) void*)g,
                                   (__attribute__((address_space(3))) void*)l, 16, 0, 0);
}

// ---------------- k_style: A[b,ci] = w[b,:].w_style[ci,:]*C_LIN + b_style[ci]
__global__ void k_style(const float* __restrict__ w, const float* __restrict__ wsty,
                        const float* __restrict__ bs, float* __restrict__ A) {
  __shared__ float wl[WD];
  __shared__ float red[256];
  const int ci0 = blockIdx.x * 64, b = blockIdx.y, tid = threadIdx.x;
  for (int i = tid; i < WD; i += 256) wl[i] = w[b * WD + i];
  __syncthreads();
  const int ci_l = tid & 63, part = tid >> 6;
  const float4* row = (const float4*)(wsty + (size_t)(ci0 + ci_l) * WD + part * 128);
  float acc = 0.f;
#pragma unroll
  for (int k = 0; k < 32; ++k) {
    float4 v = row[k];
    acc += v.x * wl[part*128 + 4*k] + v.y * wl[part*128 + 4*k+1]
         + v.z * wl[part*128 + 4*k+2] + v.w * wl[part*128 + 4*k+3];
  }
  red[tid] = acc;
  __syncthreads();
  if (part == 0)
    A[b * CIN + ci0 + ci_l] =
        (red[ci_l] + red[64+ci_l] + red[128+ci_l] + red[192+ci_l]) * C_LIN + bs[ci0 + ci_l];
}

// ---------------- k_sw: fused S + wpack (one pass over w_conv)
// wpack seg(ct,ch): cell (t*4+s)*66+co = bf16(w_conv*C_CONV), ci=ch*32+s*8+j
__global__ void k_sw(const float* __restrict__ wc, uint4* __restrict__ wp,
                     float* __restrict__ S) {
  __shared__ float wt[64][289];
  const int ct = blockIdx.x, ch = blockIdx.y, tid = threadIdx.x;
  const int co0 = ct * 64, ci0 = ch * 32;
  for (int i = tid; i < 64 * 288; i += 256) {
    int co = i / 288, r = i - co * 288;
    wt[co][r] = wc[(size_t)(co0 + co) * 4608 + (size_t)ci0 * 9 + r];
  }
  __syncthreads();
  uint4* seg = wp + (size_t)(ct * 16 + ch) * WSEG;
  for (int c = tid; c < 2304; c += 256) {
    int t = c >> 8, rem = c & 255, s = rem >> 6, co = rem & 63;
    union { unsigned short u[8]; uint4 v; } pk;
#pragma unroll
    for (int j = 0; j < 8; ++j) pk.u[j] = f2bf(wt[co][(s*8 + j) * 9 + t] * C_CONV);
    seg[(t * 4 + s) * 66 + co] = pk.v;
  }
  for (int i = tid; i < 2048; i += 256) {
    int co = i >> 5, ci = i & 31;
    float s_ = 0.f;
#pragma unroll
    for (int t = 0; t < 9; ++t) { float v = wt[co][ci * 9 + t]; s_ += v * v; }
    S[(size_t)(co0 + co) * CIN + ci0 + ci] = s_;
  }
}

// ---------------- k_demod: demod[b,co] = rsqrt(CC2 * sum_ci S*A^2 + eps)
__global__ void k_demod(const float* __restrict__ S, const float* __restrict__ A,
                        float* __restrict__ dm) {
  __shared__ float a2[CIN];
  __shared__ float red[256];
  const int co0 = blockIdx.x * 32, b = blockIdx.y, tid = threadIdx.x;
  for (int i = tid; i < CIN; i += 256) { float a = A[b * CIN + i]; a2[i] = a * a; }
  __syncthreads();
  const int co_l = tid & 31, part = tid >> 5;
  const float4* row = (const float4*)(S + (size_t)(co0 + co_l) * CIN + part * 64);
  float acc = 0.f;
#pragma unroll
  for (int k = 0; k < 16; ++k) {
    float4 v = row[k];
    acc += v.x * a2[part*64 + 4*k] + v.y * a2[part*64 + 4*k+1]
         + v.z * a2[part*64 + 4*k+2] + v.w * a2[part*64 + 4*k+3];
  }
  red[tid] = acc;
  __syncthreads();
  if (tid < 32) {
    float s_ = 0.f;
#pragma unroll
    for (int p = 0; p < 8; ++p) s_ += red[p * 32 + tid];
    dm[b * COUT + co0 + tid] = rsqrtf(CC2 * s_ + 1e-8f);
  }
}

// ---------------- k_xt: LDS-free. One wave per (b,ch,row); s=0..3 loop.
// xt[b][ch] cell (row*4+s)*66 + 1+col = bf16(x[ci][row][col] * A[ci]), halo 0.
__global__ void k_xt(const float* __restrict__ x, const float* __restrict__ A,
                     uint4* __restrict__ xt) {
  const int wid = (blockIdx.x << 2) + (threadIdx.x >> 6);   // 0..16383
  const int lane = threadIdx.x & 63;
  const int row = wid & 63, ch = (wid >> 6) & 15, b = wid >> 10;
  const float* xb = x + ((size_t)(b * CIN + ch * 32) << 12) + (row << 6) + lane;
  const float* Ab = A + b * CIN + ch * 32;
  uint4* dst = xt + (size_t)((b << 4) + ch) * 16896 + (size_t)(row << 2) * 66;
#pragma unroll
  for (int s = 0; s < 4; ++s) {
    union { unsigned short u[8]; uint4 v; } pk;
#pragma unroll
    for (int j = 0; j < 8; ++j)
      pk.u[j] = f2bf(xb[(size_t)(s * 8 + j) << 12] * Ab[s * 8 + j]);
    dst[s * 66 + 1 + lane] = pk.v;
    if (lane < 2) dst[s * 66 + lane * 65] = (uint4){0, 0, 0, 0};
  }
}

// ---------------- k_conv: 64co x 512px tiles, ci-chunk 32, pure-DMA staging
__global__ __launch_bounds__(512, 4) void k_conv(
    const uint4* __restrict__ xt, const uint4* __restrict__ wp,
    const float* __restrict__ demod, const float* __restrict__ noise,
    const float* __restrict__ sn_, const float* __restrict__ bias,
    float* __restrict__ out) {

  __shared__ __align__(16) uint4 x_lds[2640];   // 10 rows x 4 s x 66 cells
  __shared__ __align__(16) uint4 w_lds[WSEG];   // 9 t x 4 s x pitch 66
  __shared__ float dm_l[64], bi_l[64];

  const int sp = blockIdx.x, ct = blockIdx.y, b = blockIdx.z;
  const int r0 = sp * 8, co0 = ct * 64;
  const int tid = threadIdx.x, lane = tid & 63, wave = tid >> 6;
  const int l15 = lane & 15, l4 = lane >> 4;

  if (tid < 64) dm_l[tid] = demod[b * COUT + co0 + tid];
  else if (tid < 128) bi_l[tid - 64] = bias[co0 + tid - 64];
  if (sp == 0) for (int i = tid; i < 264; i += 512) x_lds[i] = (uint4){0, 0, 0, 0};
  if (sp == 7) for (int i = tid; i < 264; i += 512) x_lds[2376 + i] = (uint4){0, 0, 0, 0};

  const int lo = (r0 - 1 > 0) ? r0 - 1 : 0;
  const int hi = (r0 + 8 < 63) ? r0 + 8 : 63;
  const int cells = (hi - lo + 1) * 264;
  const int dst0 = (lo - (r0 - 1)) * 264;      // 0 or 264
  const int nI = cells >> 6, tail = cells & 63;

  f32x4 acc[4][4];
#pragma unroll
  for (int m = 0; m < 4; ++m)
#pragma unroll
    for (int f = 0; f < 4; ++f) acc[m][f] = (f32x4){0.f, 0.f, 0.f, 0.f};
  __syncthreads();

  for (int ch = 0; ch < 16; ++ch) {
    const uint4* xsrc = xt + ((size_t)(b * 16 + ch) * 64 + lo) * 264;
    const uint4* wsrc = wp + (size_t)(ct * 16 + ch) * WSEG;
    for (int i = wave; i < nI; i += 8)
      gload16(xsrc + i * 64 + lane, &x_lds[dst0 + i * 64]);
    if (tid < tail) x_lds[dst0 + nI * 64 + tid] = xsrc[nI * 64 + tid];
    for (int i = wave; i < 38; i += 8)
      gload16(wsrc + i * 64 + lane, &w_lds[i * 64]);
    __syncthreads();

#pragma unroll
    for (int t = 0; t < 9; ++t) {
      const int dh = t / 3, dw = t - dh * 3;
      s16x8 afr[4], bfr[4];
#pragma unroll
      for (int m = 0; m < 4; ++m)
        afr[m] = *(const s16x8*)&w_lds[(t * 4 + l4) * 66 + m * 16 + l15];
#pragma unroll
      for (int f = 0; f < 4; ++f)
        bfr[f] = *(const s16x8*)&x_lds[((wave + dh) * 4 + l4) * 66 + f * 16 + l15 + dw];
#pragma unroll
      for (int m = 0; m < 4; ++m)
#pragma unroll
        for (int f = 0; f < 4; ++f)
          acc[m][f] = __builtin_amdgcn_mfma_f32_16x16x32_bf16(afr[m], bfr[f], acc[m][f], 0, 0, 0);
    }
    __syncthreads();
  }

  const float sn = sn_[0];
  const int row = r0 + wave;
  float nz[4];
#pragma unroll
  for (int f = 0; f < 4; ++f) nz[f] = sn * noise[b * HW + row * 64 + f * 16 + l15];
#pragma unroll
  for (int m = 0; m < 4; ++m) {
#pragma unroll
    for (int reg = 0; reg < 4; ++reg) {
      const int co_l = m * 16 + l4 * 4 + reg;
      const float d = dm_l[co_l], bv = bi_l[co_l];
      float* op = out + ((size_t)(b * COUT + co0 + co_l)) * HW + row * 64;
#pragma unroll
      for (int f = 0; f < 4; ++f) {
        float v = d * acc[m][f][reg] + nz[f] + bv;
        op[f * 16 + l15] = (v >= 0.f) ? v : 0.2f * v;
      }
    }
  }
}

// ---------------------------------------------------------------------------
extern "C" void kernel_launch(void* const* d_in, const int* in_sizes, int n_in,
                              void* d_out, int out_size, void* d_ws, size_t ws_size,
                              hipStream_t stream) {
  (void)in_sizes; (void)n_in; (void)out_size; (void)ws_size;
  const float* x           = (const float*)d_in[0];
  const float* w           = (const float*)d_in[1];
  const float* noise       = (const float*)d_in[2];
  const float* w_style     = (const float*)d_in[3];
  const float* b_style     = (const float*)d_in[4];
  const float* w_conv      = (const float*)d_in[5];
  const float* scale_noise = (const float*)d_in[6];
  const float* bias        = (const float*)d_in[7];
  float* out = (float*)d_out;

  char* ws = (char*)d_ws;
  float* A     = (float*)(ws + WS_A);
  float* S     = (float*)(ws + WS_S);
  float* demod = (float*)(ws + WS_DM);
  uint4* wpack = (uint4*)(ws + WS_WP);
  uint4* xt    = (uint4*)(ws + WS_XT);

  k_style<<<dim3(8, 16), 256, 0, stream>>>(w, w_style, b_style, A);
  k_sw<<<dim3(8, 16), 256, 0, stream>>>(w_conv, wpack, S);
  k_demod<<<dim3(16, 16), 256, 0, stream>>>(S, A, demod);
  k_xt<<<4096, 256, 0, stream>>>(x, A, xt);
  k_conv<<<dim3(8, 8, 16), 512, 0, stream>>>(xt, wpack, demod, noise, scale_noise, bias, out);
}